// Round 1
// 654.756 us; speedup vs baseline: 1.7502x; 1.7502x over previous
//
#include <hip/hip_runtime.h>

#define B_   4
#define C_   64
#define ICn  16
#define D_   8
#define H_   128
#define W_   128
#define HW_  16384
#define MID_ 4
#define HP_  64
#define L_   4096
#define F_   144
#define FP_  160          // padded feature dim (5 x K=32 MFMA steps)
#define SCALE_ 10.0f
#define SC_  14.4269504088896f   // SCALE * log2(e)  (softmax done in exp2 domain)

typedef _Float16 half8_t __attribute__((ext_vector_type(8)));
typedef float    f32x4_t __attribute__((ext_vector_type(4)));

__device__ __forceinline__ unsigned short f2h(float x) {
    union { _Float16 h; unsigned short u; } cv;
    cv.h = (_Float16)x;
    return cv.u;
}
__device__ __forceinline__ float h2f(unsigned short u) {
    union { unsigned short u; _Float16 h; } cv;
    cv.u = u;
    return (float)cv.h;
}

// ---------------------------------------------------------------------------
// Kernel 1: three 1x1 convs on the mid depth slice. fp32 in, f16 store
// (f16 internal: 3 more mantissa bits than the bf16 pipeline that passed).
// ---------------------------------------------------------------------------
__global__ __launch_bounds__(256) void k_conv_qkv(
    const float* __restrict__ s, const float* __restrict__ g,
    const float* __restrict__ g_w, const float* __restrict__ g_b,
    const float* __restrict__ th_w, const float* __restrict__ th_b,
    const float* __restrict__ ph_w, const float* __restrict__ ph_b,
    unsigned short* __restrict__ b1, unsigned short* __restrict__ b2,
    unsigned short* __restrict__ b3)
{
    __shared__ float wq[ICn * C_], wt[ICn * C_], wp[ICn * C_];
    for (int i = threadIdx.x; i < ICn * C_; i += 256) {
        wq[i] = g_w[i]; wt[i] = th_w[i]; wp[i] = ph_w[i];
    }
    __syncthreads();

    int t = blockIdx.x * 256 + threadIdx.x;     // B_*HW_ = 65536 threads
    int hw = t & (HW_ - 1);
    int b  = t >> 14;

    float aq[ICn], at[ICn], ap[ICn];
#pragma unroll
    for (int o = 0; o < ICn; o++) { aq[o] = 0.f; at[o] = 0.f; ap[o] = 0.f; }

    for (int cc = 0; cc < C_; cc++) {
        size_t idx = ((size_t)((b * C_ + cc) * D_) + MID_) * HW_ + hw;
        float sv = s[idx];
        float gv = g[idx];
#pragma unroll
        for (int o = 0; o < ICn; o++) {
            aq[o] = fmaf(wq[o * C_ + cc], sv, aq[o]);
            at[o] = fmaf(wt[o * C_ + cc], gv, at[o]);
            ap[o] = fmaf(wp[o * C_ + cc], gv, ap[o]);
        }
    }
#pragma unroll
    for (int o = 0; o < ICn; o++) {
        b1[(size_t)(b * ICn + o) * HW_ + hw] = f2h(aq[o] + g_b[o]);
        b2[(size_t)(b * ICn + o) * HW_ + hw] = f2h(at[o] + th_b[o]);
        b3[(size_t)(b * ICn + o) * HW_ + hw] = f2h(ap[o] + ph_b[o]);
    }
}

// ---------------------------------------------------------------------------
// Kernel 2: patch extraction -> f16 MFMA-friendly layouts (pure bit-copy).
//   q [b][l][FP_]  row-major, f in [144,160) zero-padded
//   K [b][l][FP_]  row-major, zero-padded     (B-operand of QK^T reads rows)
//   Vt[b][f][L_]   transposed                 (B-operand of PV reads 8 keys)
//   f = c*9 + ki*3 + kj (torch-unfold channel-major order)
// ---------------------------------------------------------------------------
__global__ __launch_bounds__(256) void k_patchify(
    const unsigned short* __restrict__ b1, const unsigned short* __restrict__ b2,
    const unsigned short* __restrict__ b3,
    unsigned short* __restrict__ q, unsigned short* __restrict__ kr,
    unsigned short* __restrict__ vt)
{
    int t = blockIdx.x * 256 + threadIdx.x;     // B_*L_ = 16384
    int l = t & (L_ - 1);
    int b = t >> 12;
    int ph = l >> 6, pw = l & 63;
    size_t qbase = ((size_t)b * L_ + l) * FP_;

    for (int c = 0; c < ICn; c++) {
#pragma unroll
        for (int ki = 0; ki < 3; ki++) {
            int hr = 2 * ph - 1 + ki;
#pragma unroll
            for (int kj = 0; kj < 3; kj++) {
                int wc = 2 * pw - 1 + kj;
                int f = c * 9 + ki * 3 + kj;
                unsigned short qv = 0, vv = 0, kv = 0;
                if (hr >= 0 && hr < H_ && wc >= 0 && wc < W_) {
                    size_t idx = (size_t)(b * ICn + c) * HW_ + hr * W_ + wc;
                    qv = b1[idx]; vv = b2[idx]; kv = b3[idx];
                }
                q[qbase + f]  = qv;
                kr[qbase + f] = kv;
                vt[((size_t)b * F_ + f) * L_ + l] = vv;
            }
        }
    }
#pragma unroll
    for (int f = F_; f < FP_; f++) { q[qbase + f] = 0; kr[qbase + f] = 0; }
}

// ---------------------------------------------------------------------------
// Kernel 3: MFMA flash attention (v_mfma_f32_16x16x32_f16).
//   Block = 256 thr (4 waves), TM = 128 query rows (32/wave), TN = 64 keys.
//   Key-split = 2 -> grid 256 (1 block/CU, all SIMDs).  Swapped QK^T
//   (S^T = mfma(K,Q)) makes softmax in-lane; P goes through per-wave LDS
//   (XOR-swizzled) into PV's A-fragment.  Partials (unnormalized acc, m, l
//   in exp2 domain) are merged by k_combine.
// ---------------------------------------------------------------------------
#define TN_  64
#define NT_  32            // key tiles per split: (L_/TN_)/2

__global__ __launch_bounds__(256, 1) void k_attn_mfma(
    const unsigned short* __restrict__ q, const unsigned short* __restrict__ kr,
    const unsigned short* __restrict__ vt,
    float* __restrict__ pacc, float* __restrict__ pml)
{
    __shared__ unsigned short Ks[64 * FP_];       // [key][f], 320B rows, XOR (row&3)<<4
    __shared__ unsigned short Vs[F_ * TN_];       // [f][key], 128B rows, XOR (f&7)<<4
    __shared__ unsigned short Ps[4][32 * TN_];    // per-wave P [q][key], XOR (q&7)<<4

    const int t    = threadIdx.x;
    const int w    = t >> 6;
    const int lane = t & 63;
    const int l15  = lane & 15;
    const int l4   = lane >> 4;

    const int split = blockIdx.x & 1;
    const int rb    = (blockIdx.x >> 1) & 31;
    const int b     = blockIdx.x >> 6;
    const int row0  = rb * 128 + w * 32;          // wave's first query row

    // Q fragments (B-operand: col = q = l15, k-chunk = l4*8), kept in regs.
    half8_t qf[2][5];
#pragma unroll
    for (int nt = 0; nt < 2; nt++)
#pragma unroll
        for (int ks = 0; ks < 5; ks++) {
            size_t off = ((size_t)b * L_ + row0 + nt * 16 + l15) * FP_ + ks * 32 + l4 * 8;
            qf[nt][ks] = *(const half8_t*)(q + off);
        }

    f32x4_t zero4 = {0.f, 0.f, 0.f, 0.f};
    f32x4_t acc[2][9];
#pragma unroll
    for (int m = 0; m < 2; m++)
#pragma unroll
        for (int ft = 0; ft < 9; ft++) acc[m][ft] = zero4;

    float m_run[2] = {-3.0e38f, -3.0e38f};
    float l_run[2] = {0.f, 0.f};

    unsigned short* Pw = Ps[w];

    // staging index math (loop-invariant)
    int krow[5], kc[5], vrow[5], vc[5];
    bool vok[5];
#pragma unroll
    for (int it = 0; it < 5; it++) {
        unsigned idx = (unsigned)(t + it * 256);
        krow[it] = idx / 20u; kc[it] = idx % 20u;   // 20 x 16B chunks per K row
        vok[it]  = idx < 1152u;                     // 144*64*2/16 chunks
        vrow[it] = idx >> 3;  vc[it] = idx & 7;
    }

    uint4 kb[5], vb[5];
    const int kt0 = split * NT_;

    auto load_tile = [&](int kt) {
        const unsigned short* kg = kr + ((size_t)b * L_ + (size_t)kt * TN_) * FP_;
        const unsigned short* vg = vt + (size_t)b * F_ * L_ + (size_t)kt * TN_;
#pragma unroll
        for (int it = 0; it < 5; it++)
            kb[it] = *(const uint4*)(kg + (size_t)krow[it] * FP_ + kc[it] * 8);
#pragma unroll
        for (int it = 0; it < 5; it++)
            if (vok[it]) vb[it] = *(const uint4*)(vg + (size_t)vrow[it] * L_ + vc[it] * 8);
    };

    load_tile(kt0);

    for (int kt = kt0; kt < kt0 + NT_; kt++) {
        __syncthreads();   // previous tile's LDS reads complete
        // ---- write staged K/V regs -> swizzled LDS
#pragma unroll
        for (int it = 0; it < 5; it++)
            *(uint4*)((char*)Ks + krow[it] * 320 + ((kc[it] * 16) ^ ((krow[it] & 3) << 4))) = kb[it];
#pragma unroll
        for (int it = 0; it < 5; it++)
            if (vok[it])
                *(uint4*)((char*)Vs + vrow[it] * 128 + ((vc[it] * 16) ^ ((vrow[it] & 7) << 4))) = vb[it];
        __syncthreads();   // staging visible

        if (kt + 1 < kt0 + NT_) load_tile(kt + 1);   // prefetch under compute

        // ---- S^T = K Q^T: D[key][q], 4 key-tiles x 2 q-tiles, K = 160 (5x32)
        f32x4_t sacc[4][2];
#pragma unroll
        for (int mt = 0; mt < 4; mt++)
#pragma unroll
            for (int nt = 0; nt < 2; nt++) sacc[mt][nt] = zero4;

#pragma unroll
        for (int ks = 0; ks < 5; ks++) {
            half8_t af[4];
#pragma unroll
            for (int mt = 0; mt < 4; mt++) {
                int row = mt * 16 + l15;
                af[mt] = *(const half8_t*)((const char*)Ks + row * 320 +
                            ((ks * 64 + l4 * 16) ^ ((row & 3) << 4)));
            }
#pragma unroll
            for (int mt = 0; mt < 4; mt++)
#pragma unroll
                for (int nt = 0; nt < 2; nt++)
                    sacc[mt][nt] = __builtin_amdgcn_mfma_f32_16x16x32_f16(
                        af[mt], qf[nt][ks], sacc[mt][nt], 0, 0, 0);
        }
#pragma unroll
        for (int mt = 0; mt < 4; mt++)
#pragma unroll
            for (int nt = 0; nt < 2; nt++) sacc[mt][nt] *= SC_;

        // ---- online softmax, query q = nt*16 + l15 (keys live in regs)
        float alpha_q[2];
#pragma unroll
        for (int nt = 0; nt < 2; nt++) {
            float pm = sacc[0][nt][0];
#pragma unroll
            for (int mt = 0; mt < 4; mt++)
#pragma unroll
                for (int r = 0; r < 4; r++) pm = fmaxf(pm, sacc[mt][nt][r]);
            pm = fmaxf(pm, __shfl_xor(pm, 16, 64));
            pm = fmaxf(pm, __shfl_xor(pm, 32, 64));
            float mn = fmaxf(m_run[nt], pm);
            alpha_q[nt] = __builtin_amdgcn_exp2f(m_run[nt] - mn);
            m_run[nt] = mn;
            float ps = 0.f;
            int qrow = nt * 16 + l15;
#pragma unroll
            for (int mt = 0; mt < 4; mt++) {
                float e0 = __builtin_amdgcn_exp2f(sacc[mt][nt][0] - mn);
                float e1 = __builtin_amdgcn_exp2f(sacc[mt][nt][1] - mn);
                float e2 = __builtin_amdgcn_exp2f(sacc[mt][nt][2] - mn);
                float e3 = __builtin_amdgcn_exp2f(sacc[mt][nt][3] - mn);
                ps += e0 + e1 + e2 + e3;
                ushort4 pk;                      // keys mt*16 + 4*l4 + {0..3}
                pk.x = f2h(e0); pk.y = f2h(e1); pk.z = f2h(e2); pk.w = f2h(e3);
                *(ushort4*)((char*)Pw + qrow * 128 +
                            ((mt * 32 + l4 * 8) ^ ((qrow & 7) << 4))) = pk;
            }
            ps += __shfl_xor(ps, 16, 64);
            ps += __shfl_xor(ps, 32, 64);
            l_run[nt] = l_run[nt] * alpha_q[nt] + ps;
        }

        // ---- rescale acc by alpha of its own row q' = m*16 + 4*l4 + r
#pragma unroll
        for (int m = 0; m < 2; m++) {
            f32x4_t av;
#pragma unroll
            for (int r = 0; r < 4; r++)
                av[r] = __shfl(alpha_q[m], (lane & 48) | (4 * l4 + r), 64);
#pragma unroll
            for (int ft = 0; ft < 9; ft++)
#pragma unroll
                for (int r = 0; r < 4; r++) acc[m][ft][r] *= av[r];
        }

        // ---- PV: D[q][f] += P V   (A = P from LDS, B = V from LDS)
#pragma unroll
        for (int ks = 0; ks < 2; ks++) {
            half8_t pa[2];
#pragma unroll
            for (int m = 0; m < 2; m++) {
                int qrow = m * 16 + l15;
                pa[m] = *(const half8_t*)((const char*)Pw + qrow * 128 +
                            ((ks * 64 + l4 * 16) ^ ((qrow & 7) << 4)));
            }
#pragma unroll
            for (int ft = 0; ft < 9; ft++) {
                int f = ft * 16 + l15;
                half8_t vbf = *(const half8_t*)((const char*)Vs + f * 128 +
                            ((ks * 64 + l4 * 16) ^ ((f & 7) << 4)));
#pragma unroll
                for (int m = 0; m < 2; m++)
                    acc[m][ft] = __builtin_amdgcn_mfma_f32_16x16x32_f16(
                        pa[m], vbf, acc[m][ft], 0, 0, 0);
            }
        }
    }

    // ---- epilogue: store unnormalized acc + (m,l); k_combine normalizes
    const size_t prow0 = ((size_t)split * B_ + b) * L_ + row0;
#pragma unroll
    for (int m = 0; m < 2; m++)
#pragma unroll
        for (int r = 0; r < 4; r++) {
            size_t R = prow0 + m * 16 + 4 * l4 + r;
#pragma unroll
            for (int ft = 0; ft < 9; ft++)
                pacc[R * F_ + ft * 16 + l15] = acc[m][ft][r];
        }
    if (l4 == 0) {
#pragma unroll
        for (int nt = 0; nt < 2; nt++) {
            size_t R = prow0 + nt * 16 + l15;
            pml[R * 2 + 0] = m_run[nt];
            pml[R * 2 + 1] = l_run[nt];
        }
    }
}

// ---------------------------------------------------------------------------
// Kernel 3b: merge the two key-split partials -> zi [b][l][144] fp32.
// ---------------------------------------------------------------------------
__global__ __launch_bounds__(256) void k_combine(
    const float* __restrict__ pacc, const float* __restrict__ pml,
    float* __restrict__ zi)
{
    int tg = blockIdx.x * 256 + threadIdx.x;     // B_*L_*36 = 589824
    int row = tg / 36;
    int c = tg - row * 36;
    float m0 = pml[(size_t)row * 2],                    l0 = pml[(size_t)row * 2 + 1];
    float m1 = pml[((size_t)(B_ * L_) + row) * 2],      l1 = pml[((size_t)(B_ * L_) + row) * 2 + 1];
    float mm = fmaxf(m0, m1);
    float w0 = __builtin_amdgcn_exp2f(m0 - mm);
    float w1 = __builtin_amdgcn_exp2f(m1 - mm);
    float inv = 1.f / (l0 * w0 + l1 * w1);
    float4 a0 = *(const float4*)&pacc[(size_t)row * F_ + c * 4];
    float4 a1 = *(const float4*)&pacc[((size_t)(B_ * L_) + row) * F_ + c * 4];
    float4 o;
    o.x = (a0.x * w0 + a1.x * w1) * inv;
    o.y = (a0.y * w0 + a1.y * w1) * inv;
    o.z = (a0.z * w0 + a1.z * w1) * inv;
    o.w = (a0.w * w0 + a1.w * w1) * inv;
    *(float4*)&zi[(size_t)row * F_ + c * 4] = o;
}

// ---------------------------------------------------------------------------
// Kernel 4: fold (overlap-add) + mask normalization.  (unchanged)
// ---------------------------------------------------------------------------
__global__ __launch_bounds__(256) void k_fold(
    const float* __restrict__ zi, float* __restrict__ z)
{
    int t = blockIdx.x * 256 + threadIdx.x;   // B_*ICn*HW_ = 1,048,576
    int hw = t & (HW_ - 1);
    int h = hw >> 7, w = hw & 127;
    int ic = (t >> 14) & 15;
    int b  = t >> 18;
    int hh = h + 1, ww = w + 1;

    int iArr[2], phArr[2], nh = 0;
#pragma unroll
    for (int i = 0; i < 3; i++) {
        int u = hh - i;
        if (u >= 0 && (u & 1) == 0 && (u >> 1) < HP_) { iArr[nh] = i; phArr[nh] = u >> 1; nh++; }
    }
    int jArr[2], pwArr[2], nw = 0;
#pragma unroll
    for (int j = 0; j < 3; j++) {
        int u = ww - j;
        if (u >= 0 && (u & 1) == 0 && (u >> 1) < HP_) { jArr[nw] = j; pwArr[nw] = u >> 1; nw++; }
    }
    float acc = 0.f;
    for (int a = 0; a < nh; a++)
        for (int c2 = 0; c2 < nw; c2++) {
            int l = phArr[a] * 64 + pwArr[c2];
            acc += zi[((size_t)b * L_ + l) * F_ + ic * 9 + iArr[a] * 3 + jArr[c2]];
        }
    z[t] = acc / (float)(nh * nw);
}

// ---------------------------------------------------------------------------
// Kernel 5: out = s + W_w @ z + W_bias, broadcast over D.  (unchanged)
// ---------------------------------------------------------------------------
__global__ __launch_bounds__(256) void k_out(
    const float* __restrict__ s, const float* __restrict__ z,
    const float* __restrict__ Ww, const float* __restrict__ Wb,
    float* __restrict__ out)
{
    int t = blockIdx.x * 256 + threadIdx.x;   // 4,194,304 threads
    size_t e0 = (size_t)t * 8;
    int hw = (int)(e0 & (HW_ - 1));
    int c  = (int)((e0 >> 17) & 63);
    int b  = (int)(e0 >> 23);

    float bias = Wb[c];
    float acc[8];
#pragma unroll
    for (int i = 0; i < 8; i++) acc[i] = bias;

    const float* zb = z + (size_t)b * ICn * HW_ + hw;
#pragma unroll
    for (int ic = 0; ic < ICn; ic++) {
        float wv = Ww[c * ICn + ic];
        const float4* zp = (const float4*)(zb + (size_t)ic * HW_);
        float4 z0 = zp[0], z1 = zp[1];
        acc[0] = fmaf(wv, z0.x, acc[0]); acc[1] = fmaf(wv, z0.y, acc[1]);
        acc[2] = fmaf(wv, z0.z, acc[2]); acc[3] = fmaf(wv, z0.w, acc[3]);
        acc[4] = fmaf(wv, z1.x, acc[4]); acc[5] = fmaf(wv, z1.y, acc[5]);
        acc[6] = fmaf(wv, z1.z, acc[6]); acc[7] = fmaf(wv, z1.w, acc[7]);
    }

    const float4* sp = (const float4*)(s + e0);
    float4 s0 = sp[0], s1 = sp[1];
    float4 o0 = make_float4(s0.x + acc[0], s0.y + acc[1], s0.z + acc[2], s0.w + acc[3]);
    float4 o1 = make_float4(s1.x + acc[4], s1.y + acc[5], s1.z + acc[6], s1.w + acc[7]);
    float4* op = (float4*)(out + e0);
    op[0] = o0; op[1] = o1;
}

// ---------------------------------------------------------------------------
extern "C" void kernel_launch(void* const* d_in, const int* in_sizes, int n_in,
                              void* d_out, int out_size, void* d_ws, size_t ws_size,
                              hipStream_t stream)
{
    (void)in_sizes; (void)n_in; (void)out_size; (void)ws_size;
    const float* s    = (const float*)d_in[0];
    const float* g    = (const float*)d_in[1];
    const float* g_w  = (const float*)d_in[2];
    const float* g_b  = (const float*)d_in[3];
    const float* th_w = (const float*)d_in[4];
    const float* th_b = (const float*)d_in[5];
    const float* ph_w = (const float*)d_in[6];
    const float* ph_b = (const float*)d_in[7];
    const float* W_w  = (const float*)d_in[8];
    const float* W_b  = (const float*)d_in[9];
    float* out = (float*)d_out;

    // Workspace layout (high-water ~38.8 MB):
    //   [0, 6M)            b1,b2,b3 f16 (dead after patchify)
    //   [6M, 11.25M)       q  f16 [b][l][160]
    //   [11.25M, 16M)      K  f16 [b][l][160]
    //   [16M, 20.5M)       Vt f16 [b][144][L]
    //   [20.5M, 38.5M)     pacc fp32 [2][b][l][144]
    //   [38.5M, 38.8M)     pml  fp32 [2][b][l][2]
    //   overlays (post-attn): zi fp32 at 0 (9.44M), z fp32 at 9.44M (4M)
    char* base = (char*)d_ws;
    const size_t CONV_B = 2097152;
    unsigned short* b1 = (unsigned short*)(base);
    unsigned short* b2 = (unsigned short*)(base + CONV_B);
    unsigned short* b3 = (unsigned short*)(base + 2 * CONV_B);
    unsigned short* qq = (unsigned short*)(base + 6291456);
    unsigned short* kk = (unsigned short*)(base + 11534336);
    unsigned short* vv = (unsigned short*)(base + 16777216);
    float*          pacc = (float*)(base + 21499904);
    float*          pml  = (float*)(base + 40374272);
    float*          zi   = (float*)(base);             // overlay: b1-3 + part of q (dead)
    float*          zz   = (float*)(base + 9437184);   // overlay: rest of q/K (dead)

    hipLaunchKernelGGL(k_conv_qkv, dim3(256),   dim3(256), 0, stream,
                       s, g, g_w, g_b, th_w, th_b, ph_w, ph_b, b1, b2, b3);
    hipLaunchKernelGGL(k_patchify, dim3(64),    dim3(256), 0, stream, b1, b2, b3, qq, kk, vv);
    hipLaunchKernelGGL(k_attn_mfma, dim3(256),  dim3(256), 0, stream, qq, kk, vv, pacc, pml);
    hipLaunchKernelGGL(k_combine,  dim3(2304),  dim3(256), 0, stream, pacc, pml, zi);
    hipLaunchKernelGGL(k_fold,     dim3(4096),  dim3(256), 0, stream, zi, zz);
    hipLaunchKernelGGL(k_out,      dim3(16384), dim3(256), 0, stream, s, zz, W_w, W_b, out);
}

// Round 2
// 624.613 us; speedup vs baseline: 1.8347x; 1.0483x over previous
//
#include <hip/hip_runtime.h>

#define B_   4
#define C_   64
#define ICn  16
#define D_   8
#define H_   128
#define W_   128
#define HW_  16384
#define MID_ 4
#define HP_  64
#define L_   4096
#define F_   144
#define FP_  160          // padded feature dim (5 x K=32 MFMA steps)
#define SCALE_ 10.0f
#define SC_  14.4269504088896f   // SCALE * log2(e)  (softmax done in exp2 domain)

typedef _Float16 half8_t __attribute__((ext_vector_type(8)));
typedef float    f32x4_t __attribute__((ext_vector_type(4)));

__device__ __forceinline__ unsigned short f2h(float x) {
    union { _Float16 h; unsigned short u; } cv;
    cv.h = (_Float16)x;
    return cv.u;
}

// ---------------------------------------------------------------------------
// Kernel 1: three 1x1 convs on the mid depth slice. fp32 in, f16 store.
// Output layout: [b][hw][16] (channel-inner) so patchify can vector-load.
// ---------------------------------------------------------------------------
__global__ __launch_bounds__(256) void k_conv_qkv(
    const float* __restrict__ s, const float* __restrict__ g,
    const float* __restrict__ g_w, const float* __restrict__ g_b,
    const float* __restrict__ th_w, const float* __restrict__ th_b,
    const float* __restrict__ ph_w, const float* __restrict__ ph_b,
    unsigned short* __restrict__ b1, unsigned short* __restrict__ b2,
    unsigned short* __restrict__ b3)
{
    __shared__ float wq[ICn * C_], wt[ICn * C_], wp[ICn * C_];
    for (int i = threadIdx.x; i < ICn * C_; i += 256) {
        wq[i] = g_w[i]; wt[i] = th_w[i]; wp[i] = ph_w[i];
    }
    __syncthreads();

    int t = blockIdx.x * 256 + threadIdx.x;     // B_*HW_ = 65536 threads
    int hw = t & (HW_ - 1);
    int b  = t >> 14;

    float aq[ICn], at[ICn], ap[ICn];
#pragma unroll
    for (int o = 0; o < ICn; o++) { aq[o] = 0.f; at[o] = 0.f; ap[o] = 0.f; }

    for (int cc = 0; cc < C_; cc++) {
        size_t idx = ((size_t)((b * C_ + cc) * D_) + MID_) * HW_ + hw;
        float sv = s[idx];
        float gv = g[idx];
#pragma unroll
        for (int o = 0; o < ICn; o++) {
            aq[o] = fmaf(wq[o * C_ + cc], sv, aq[o]);
            at[o] = fmaf(wt[o * C_ + cc], gv, at[o]);
            ap[o] = fmaf(wp[o * C_ + cc], gv, ap[o]);
        }
    }
    unsigned short tq[16], tt[16], tp[16];
#pragma unroll
    for (int o = 0; o < ICn; o++) {
        tq[o] = f2h(aq[o] + g_b[o]);
        tt[o] = f2h(at[o] + th_b[o]);
        tp[o] = f2h(ap[o] + ph_b[o]);
    }
    size_t base = (size_t)(b * HW_ + hw) * 16;
    *(uint4*)(b1 + base) = *(uint4*)tq; *(uint4*)(b1 + base + 8) = *(uint4*)(tq + 8);
    *(uint4*)(b2 + base) = *(uint4*)tt; *(uint4*)(b2 + base + 8) = *(uint4*)(tt + 8);
    *(uint4*)(b3 + base) = *(uint4*)tp; *(uint4*)(b3 + base + 8) = *(uint4*)(tp + 8);
}

// ---------------------------------------------------------------------------
// Kernel 2: patch extraction. Feature axis reordered: f' = pos*16 + c
// (pos = ki*3+kj). One thread per (b, l, pos): 32B vector load per tensor,
// 32B vector stores to q/K; Vt stores coalesced across lanes (consecutive l).
//   q [b][l][FP_], K [b][l][FP_] zero-padded; Vt[b][f'][L_].
// ---------------------------------------------------------------------------
__global__ __launch_bounds__(256) void k_patchify(
    const unsigned short* __restrict__ b1, const unsigned short* __restrict__ b2,
    const unsigned short* __restrict__ b3,
    unsigned short* __restrict__ q, unsigned short* __restrict__ kr,
    unsigned short* __restrict__ vt)
{
    int t = blockIdx.x * 256 + threadIdx.x;     // B_*9*L_ = 147456
    int l = t & (L_ - 1);
    int rest = t >> 12;         // b*9 + pos, 0..35
    int b = rest / 9;
    int pos = rest - b * 9;
    int ki = pos / 3, kj = pos - ki * 3;
    int ph = l >> 6, pw = l & 63;
    int hr = 2 * ph - 1 + ki;
    int wc = 2 * pw - 1 + kj;

    union { uint4 v[2]; unsigned short u[16]; } qd, vd, kd;
    uint4 z4 = {0u, 0u, 0u, 0u};
    qd.v[0] = qd.v[1] = z4; vd.v[0] = vd.v[1] = z4; kd.v[0] = kd.v[1] = z4;
    if (hr >= 0 && hr < H_ && wc >= 0 && wc < W_) {
        size_t base = (size_t)(b * HW_ + hr * W_ + wc) * 16;
        qd.v[0] = *(const uint4*)(b1 + base); qd.v[1] = *(const uint4*)(b1 + base + 8);
        vd.v[0] = *(const uint4*)(b2 + base); vd.v[1] = *(const uint4*)(b2 + base + 8);
        kd.v[0] = *(const uint4*)(b3 + base); kd.v[1] = *(const uint4*)(b3 + base + 8);
    }
    size_t qbase = ((size_t)b * L_ + l) * FP_ + pos * 16;
    *(uint4*)(q + qbase) = qd.v[0];  *(uint4*)(q + qbase + 8) = qd.v[1];
    *(uint4*)(kr + qbase) = kd.v[0]; *(uint4*)(kr + qbase + 8) = kd.v[1];

    size_t vbase = ((size_t)b * F_ + pos * 16) * L_ + l;
#pragma unroll
    for (int c = 0; c < 16; c++) vt[vbase + (size_t)c * L_] = vd.u[c];

    if (pos == 0) {   // zero-pad f in [144,160)
        size_t pb = ((size_t)b * L_ + l) * FP_ + F_;
        *(uint4*)(q + pb) = z4;  *(uint4*)(q + pb + 8) = z4;
        *(uint4*)(kr + pb) = z4; *(uint4*)(kr + pb + 8) = z4;
    }
}

// ---------------------------------------------------------------------------
// Kernel 3: MFMA flash attention (v_mfma_f32_16x16x32_f16).
//   Block = 256 thr (4 waves), TM = 64 query rows (16/wave), TN = 64 keys.
//   Key-split = 2 -> grid 512 = 2 blocks/CU (2 waves/SIMD for latency hiding).
//   Swapped QK^T (S^T = mfma(K,Q)) -> in-lane softmax; P via per-wave LDS.
//   Ks rows padded to 384B so XOR (row&7)<<4 gives conflict-free ds_read_b128.
// ---------------------------------------------------------------------------
#define TN_  64
#define NT_  32            // key tiles per split: (L_/TN_)/2
#define KSB  384           // Ks row stride in bytes (320 data + 64 pad)

__global__ __launch_bounds__(256, 1) void k_attn_mfma(
    const unsigned short* __restrict__ q, const unsigned short* __restrict__ kr,
    const unsigned short* __restrict__ vt,
    float* __restrict__ pacc, float* __restrict__ pml)
{
    __shared__ unsigned short Ks[64 * 192];       // [key][f], 384B rows, XOR (row&7)<<4
    __shared__ unsigned short Vs[F_ * TN_];       // [f][key], 128B rows, XOR (f&7)<<4
    __shared__ unsigned short Ps[4][16 * TN_];    // per-wave P [q][key], XOR (q&7)<<4

    const int t    = threadIdx.x;
    const int w    = t >> 6;
    const int lane = t & 63;
    const int l15  = lane & 15;
    const int l4   = lane >> 4;

    const int split = blockIdx.x & 1;
    const int rb    = (blockIdx.x >> 1) & 63;
    const int b     = blockIdx.x >> 7;
    const int row0  = rb * 64 + w * 16;           // wave's first query row

    // Q fragments (B-operand: col = q = l15, k-chunk = l4*8), kept in regs.
    half8_t qf[5];
#pragma unroll
    for (int ks = 0; ks < 5; ks++) {
        size_t off = ((size_t)b * L_ + row0 + l15) * FP_ + ks * 32 + l4 * 8;
        qf[ks] = *(const half8_t*)(q + off);
    }

    f32x4_t zero4 = {0.f, 0.f, 0.f, 0.f};
    f32x4_t acc[9];
#pragma unroll
    for (int ft = 0; ft < 9; ft++) acc[ft] = zero4;

    float m_run = -3.0e38f;
    float l_run = 0.f;

    unsigned short* Pw = Ps[w];

    // staging index math (loop-invariant)
    int krow[5], kc[5], vrow[5], vc[5];
    bool vok[5];
#pragma unroll
    for (int it = 0; it < 5; it++) {
        unsigned idx = (unsigned)(t + it * 256);
        krow[it] = idx / 20u; kc[it] = idx % 20u;   // 20 x 16B chunks per K row
        vok[it]  = idx < 1152u;                     // 144*64*2/16 chunks
        vrow[it] = idx >> 3;  vc[it] = idx & 7;
    }

    uint4 kb[5], vb[5];
    const int kt0 = split * NT_;

    auto load_tile = [&](int kt) {
        const unsigned short* kg = kr + ((size_t)b * L_ + (size_t)kt * TN_) * FP_;
        const unsigned short* vg = vt + (size_t)b * F_ * L_ + (size_t)kt * TN_;
#pragma unroll
        for (int it = 0; it < 5; it++)
            kb[it] = *(const uint4*)(kg + (size_t)krow[it] * FP_ + kc[it] * 8);
#pragma unroll
        for (int it = 0; it < 5; it++)
            if (vok[it]) vb[it] = *(const uint4*)(vg + (size_t)vrow[it] * L_ + vc[it] * 8);
    };

    load_tile(kt0);

    for (int kt = kt0; kt < kt0 + NT_; kt++) {
        __syncthreads();   // previous tile's LDS reads complete
        // ---- write staged K/V regs -> swizzled LDS
#pragma unroll
        for (int it = 0; it < 5; it++)
            *(uint4*)((char*)Ks + krow[it] * KSB + ((kc[it] * 16) ^ ((krow[it] & 7) << 4))) = kb[it];
#pragma unroll
        for (int it = 0; it < 5; it++)
            if (vok[it])
                *(uint4*)((char*)Vs + vrow[it] * 128 + ((vc[it] * 16) ^ ((vrow[it] & 7) << 4))) = vb[it];
        __syncthreads();   // staging visible

        if (kt + 1 < kt0 + NT_) load_tile(kt + 1);   // prefetch under compute

        // ---- S^T = K Q^T: D[key][q], 4 key-tiles, K = 160 (5x32)
        f32x4_t sacc[4];
#pragma unroll
        for (int mt = 0; mt < 4; mt++) sacc[mt] = zero4;

#pragma unroll
        for (int ks = 0; ks < 5; ks++) {
            half8_t af[4];
#pragma unroll
            for (int mt = 0; mt < 4; mt++) {
                int row = mt * 16 + l15;
                af[mt] = *(const half8_t*)((const char*)Ks + row * KSB +
                            ((ks * 64 + l4 * 16) ^ ((row & 7) << 4)));
            }
#pragma unroll
            for (int mt = 0; mt < 4; mt++)
                sacc[mt] = __builtin_amdgcn_mfma_f32_16x16x32_f16(
                    af[mt], qf[ks], sacc[mt], 0, 0, 0);
        }
#pragma unroll
        for (int mt = 0; mt < 4; mt++) sacc[mt] *= SC_;

        // ---- online softmax, query q = l15 (this lane holds keys mt*16+4*l4+r)
        float pm = sacc[0][0];
#pragma unroll
        for (int mt = 0; mt < 4; mt++)
#pragma unroll
            for (int r = 0; r < 4; r++) pm = fmaxf(pm, sacc[mt][r]);
        pm = fmaxf(pm, __shfl_xor(pm, 16, 64));
        pm = fmaxf(pm, __shfl_xor(pm, 32, 64));
        float mn = fmaxf(m_run, pm);
        float alpha_q = __builtin_amdgcn_exp2f(m_run - mn);
        m_run = mn;
        float ps = 0.f;
        int qrow = l15;
#pragma unroll
        for (int mt = 0; mt < 4; mt++) {
            float e0 = __builtin_amdgcn_exp2f(sacc[mt][0] - mn);
            float e1 = __builtin_amdgcn_exp2f(sacc[mt][1] - mn);
            float e2 = __builtin_amdgcn_exp2f(sacc[mt][2] - mn);
            float e3 = __builtin_amdgcn_exp2f(sacc[mt][3] - mn);
            ps += e0 + e1 + e2 + e3;
            ushort4 pk;                      // keys mt*16 + 4*l4 + {0..3}
            pk.x = f2h(e0); pk.y = f2h(e1); pk.z = f2h(e2); pk.w = f2h(e3);
            *(ushort4*)((char*)Pw + qrow * 128 +
                        ((mt * 32 + l4 * 8) ^ ((qrow & 7) << 4))) = pk;
        }
        ps += __shfl_xor(ps, 16, 64);
        ps += __shfl_xor(ps, 32, 64);
        l_run = l_run * alpha_q + ps;

        // ---- rescale acc by alpha of its own row q' = 4*l4 + r
        f32x4_t av;
#pragma unroll
        for (int r = 0; r < 4; r++)
            av[r] = __shfl(alpha_q, (lane & 48) | (4 * l4 + r), 64);
#pragma unroll
        for (int ft = 0; ft < 9; ft++)
#pragma unroll
            for (int r = 0; r < 4; r++) acc[ft][r] *= av[r];

        // ---- PV: D[q][f'] += P V   (A = P from LDS, B = V from LDS)
#pragma unroll
        for (int ks = 0; ks < 2; ks++) {
            half8_t pa = *(const half8_t*)((const char*)Pw + l15 * 128 +
                            ((ks * 64 + l4 * 16) ^ ((l15 & 7) << 4)));
#pragma unroll
            for (int ft = 0; ft < 9; ft++) {
                int f = ft * 16 + l15;
                half8_t vbf = *(const half8_t*)((const char*)Vs + f * 128 +
                            ((ks * 64 + l4 * 16) ^ ((f & 7) << 4)));
                acc[ft] = __builtin_amdgcn_mfma_f32_16x16x32_f16(
                    pa, vbf, acc[ft], 0, 0, 0);
            }
        }
    }

    // ---- epilogue: store unnormalized acc + (m,l); k_combine normalizes
    const size_t prow0 = ((size_t)split * B_ + b) * L_ + row0;
#pragma unroll
    for (int r = 0; r < 4; r++) {
        size_t R = prow0 + 4 * l4 + r;
#pragma unroll
        for (int ft = 0; ft < 9; ft++)
            pacc[R * F_ + ft * 16 + l15] = acc[ft][r];
    }
    if (l4 == 0) {
        size_t R = prow0 + l15;
        pml[R * 2 + 0] = m_run;
        pml[R * 2 + 1] = l_run;
    }
}

// ---------------------------------------------------------------------------
// Kernel 3b: merge the two key-split partials -> zi [b][l][144] fp32.
// ---------------------------------------------------------------------------
__global__ __launch_bounds__(256) void k_combine(
    const float* __restrict__ pacc, const float* __restrict__ pml,
    float* __restrict__ zi)
{
    int tg = blockIdx.x * 256 + threadIdx.x;     // B_*L_*36 = 589824
    int row = tg / 36;
    int c = tg - row * 36;
    float m0 = pml[(size_t)row * 2],                    l0 = pml[(size_t)row * 2 + 1];
    float m1 = pml[((size_t)(B_ * L_) + row) * 2],      l1 = pml[((size_t)(B_ * L_) + row) * 2 + 1];
    float mm = fmaxf(m0, m1);
    float w0 = __builtin_amdgcn_exp2f(m0 - mm);
    float w1 = __builtin_amdgcn_exp2f(m1 - mm);
    float inv = 1.f / (l0 * w0 + l1 * w1);
    float4 a0 = *(const float4*)&pacc[(size_t)row * F_ + c * 4];
    float4 a1 = *(const float4*)&pacc[((size_t)(B_ * L_) + row) * F_ + c * 4];
    float4 o;
    o.x = (a0.x * w0 + a1.x * w1) * inv;
    o.y = (a0.y * w0 + a1.y * w1) * inv;
    o.z = (a0.z * w0 + a1.z * w1) * inv;
    o.w = (a0.w * w0 + a1.w * w1) * inv;
    *(float4*)&zi[(size_t)row * F_ + c * 4] = o;
}

// ---------------------------------------------------------------------------
// Kernel 4: fold (overlap-add) + mask normalization. One thread per (b,hw),
// all 16 channels at once via float4 loads (f' = pos*16 + c layout).
// z output: [b][ic][hw].
// ---------------------------------------------------------------------------
__global__ __launch_bounds__(256) void k_fold(
    const float* __restrict__ zi, float* __restrict__ z)
{
    int t = blockIdx.x * 256 + threadIdx.x;   // B_*HW_ = 65536
    int hw = t & (HW_ - 1);
    int b  = t >> 14;
    int h = hw >> 7, w = hw & 127;
    int hh = h + 1, ww = w + 1;

    int iArr[2], phArr[2], nh = 0;
#pragma unroll
    for (int i = 0; i < 3; i++) {
        int u = hh - i;
        if (u >= 0 && (u & 1) == 0 && (u >> 1) < HP_) { iArr[nh] = i; phArr[nh] = u >> 1; nh++; }
    }
    int jArr[2], pwArr[2], nw = 0;
#pragma unroll
    for (int j = 0; j < 3; j++) {
        int u = ww - j;
        if (u >= 0 && (u & 1) == 0 && (u >> 1) < HP_) { jArr[nw] = j; pwArr[nw] = u >> 1; nw++; }
    }
    float acc[16];
#pragma unroll
    for (int k = 0; k < 16; k++) acc[k] = 0.f;

    for (int a = 0; a < nh; a++)
        for (int c2 = 0; c2 < nw; c2++) {
            int l = phArr[a] * 64 + pwArr[c2];
            int pos = iArr[a] * 3 + jArr[c2];
            const float4* zp = (const float4*)(zi + ((size_t)b * L_ + l) * F_ + pos * 16);
            float4 a0 = zp[0], a1 = zp[1], a2 = zp[2], a3 = zp[3];
            acc[0] += a0.x; acc[1] += a0.y; acc[2]  += a0.z; acc[3]  += a0.w;
            acc[4] += a1.x; acc[5] += a1.y; acc[6]  += a1.z; acc[7]  += a1.w;
            acc[8] += a2.x; acc[9] += a2.y; acc[10] += a2.z; acc[11] += a2.w;
            acc[12] += a3.x; acc[13] += a3.y; acc[14] += a3.z; acc[15] += a3.w;
        }
    float inv = 1.0f / (float)(nh * nw);
#pragma unroll
    for (int ic = 0; ic < 16; ic++)
        z[((size_t)(b * ICn + ic) << 14) + hw] = acc[ic] * inv;
}

// ---------------------------------------------------------------------------
// Kernel 5: out = s + W_w @ z + W_bias, broadcast over D. One thread per
// (b,c,hw8): compute W.z once, reuse across the 8 d-planes (8x less z L2
// traffic and 8x fewer FMAs than before).
// ---------------------------------------------------------------------------
__global__ __launch_bounds__(256) void k_out(
    const float* __restrict__ s, const float* __restrict__ z,
    const float* __restrict__ Ww, const float* __restrict__ Wb,
    float* __restrict__ out)
{
    int t = blockIdx.x * 256 + threadIdx.x;   // B_*C_*HW_/8 = 524288 threads
    size_t e0 = (size_t)t * 8;
    int hw = (int)(e0 & (HW_ - 1));
    int c  = (int)((e0 >> 14) & 63);
    int b  = (int)(e0 >> 20);

    float bias = Wb[c];
    float acc[8];
#pragma unroll
    for (int i = 0; i < 8; i++) acc[i] = bias;

    const float* zb = z + ((size_t)(b * ICn) << 14) + hw;
#pragma unroll
    for (int ic = 0; ic < ICn; ic++) {
        float wv = Ww[c * ICn + ic];
        const float4* zp = (const float4*)(zb + ((size_t)ic << 14));
        float4 z0 = zp[0], z1 = zp[1];
        acc[0] = fmaf(wv, z0.x, acc[0]); acc[1] = fmaf(wv, z0.y, acc[1]);
        acc[2] = fmaf(wv, z0.z, acc[2]); acc[3] = fmaf(wv, z0.w, acc[3]);
        acc[4] = fmaf(wv, z1.x, acc[4]); acc[5] = fmaf(wv, z1.y, acc[5]);
        acc[6] = fmaf(wv, z1.z, acc[6]); acc[7] = fmaf(wv, z1.w, acc[7]);
    }

#pragma unroll
    for (int d = 0; d < D_; d++) {
        size_t off = (((size_t)(b * C_ + c) * D_ + d) << 14) + hw;
        const float4* sp = (const float4*)(s + off);
        float4 s0 = sp[0], s1 = sp[1];
        float4 o0 = make_float4(s0.x + acc[0], s0.y + acc[1], s0.z + acc[2], s0.w + acc[3]);
        float4 o1 = make_float4(s1.x + acc[4], s1.y + acc[5], s1.z + acc[6], s1.w + acc[7]);
        float4* op = (float4*)(out + off);
        op[0] = o0; op[1] = o1;
    }
}

// ---------------------------------------------------------------------------
extern "C" void kernel_launch(void* const* d_in, const int* in_sizes, int n_in,
                              void* d_out, int out_size, void* d_ws, size_t ws_size,
                              hipStream_t stream)
{
    (void)in_sizes; (void)n_in; (void)out_size; (void)ws_size;
    const float* s    = (const float*)d_in[0];
    const float* g    = (const float*)d_in[1];
    const float* g_w  = (const float*)d_in[2];
    const float* g_b  = (const float*)d_in[3];
    const float* th_w = (const float*)d_in[4];
    const float* th_b = (const float*)d_in[5];
    const float* ph_w = (const float*)d_in[6];
    const float* ph_b = (const float*)d_in[7];
    const float* W_w  = (const float*)d_in[8];
    const float* W_b  = (const float*)d_in[9];
    float* out = (float*)d_out;

    // Workspace layout (high-water ~38.8 MB, same as previous round):
    //   [0, 6M)        b1,b2,b3 f16 [b][hw][16] (dead after patchify)
    //   [6M, 11.25M)   q  f16 [b][l][160]
    //   [11.25M,16.5M) K  f16 [b][l][160]
    //   [16.5M,21.2M)  Vt f16 [b][144][L]
    //   [21.2M,40.1M)  pacc fp32 [2][b][l][144]
    //   [40.1M,40.4M)  pml  fp32 [2][b][l][2]
    //   overlays (post-attn): zi fp32 at 0 (9.44M), z fp32 at 9.44M (4M)
    char* base = (char*)d_ws;
    const size_t CONV_B = 2097152;
    unsigned short* b1 = (unsigned short*)(base);
    unsigned short* b2 = (unsigned short*)(base + CONV_B);
    unsigned short* b3 = (unsigned short*)(base + 2 * CONV_B);
    unsigned short* qq = (unsigned short*)(base + 6291456);
    unsigned short* kk = (unsigned short*)(base + 11534336);
    unsigned short* vv = (unsigned short*)(base + 16777216);
    float*          pacc = (float*)(base + 21495808);
    float*          pml  = (float*)(base + 40370176);
    float*          zi   = (float*)(base);             // overlay: conv planes + q head (dead)
    float*          zz   = (float*)(base + 9437184);   // overlay: rest of q/K (dead)

    hipLaunchKernelGGL(k_conv_qkv, dim3(256),   dim3(256), 0, stream,
                       s, g, g_w, g_b, th_w, th_b, ph_w, ph_b, b1, b2, b3);
    hipLaunchKernelGGL(k_patchify, dim3(576),   dim3(256), 0, stream, b1, b2, b3, qq, kk, vv);
    hipLaunchKernelGGL(k_attn_mfma, dim3(512),  dim3(256), 0, stream, qq, kk, vv, pacc, pml);
    hipLaunchKernelGGL(k_combine,  dim3(2304),  dim3(256), 0, stream, pacc, pml, zi);
    hipLaunchKernelGGL(k_fold,     dim3(256),   dim3(256), 0, stream, zi, zz);
    hipLaunchKernelGGL(k_out,      dim3(2048),  dim3(256), 0, stream, s, zz, W_w, W_b, out);
}

// Round 3
// 498.200 us; speedup vs baseline: 2.3002x; 1.2537x over previous
//
#include <hip/hip_runtime.h>

#define B_   4
#define C_   64
#define ICn  16
#define D_   8
#define H_   128
#define W_   128
#define HW_  16384
#define MID_ 4
#define HP_  64
#define L_   4096
#define F_   144
#define FP_  160          // padded feature dim for q (5 x K=32 MFMA steps)
#define KRS_ 192          // K row stride in shorts (384 B rows, for in-row XOR swizzle)
#define VTR_ 192          // Vt rows per batch (144 data + 48 pad, pad never read)
#define SCALE_ 10.0f
#define SC_  14.4269504088896f   // SCALE * log2(e)  (softmax done in exp2 domain)

typedef _Float16 half8_t __attribute__((ext_vector_type(8)));
typedef float    f32x4_t __attribute__((ext_vector_type(4)));

__device__ __forceinline__ unsigned short f2h(float x) {
    union { _Float16 h; unsigned short u; } cv;
    cv.h = (_Float16)x;
    return cv.u;
}

// ---------------------------------------------------------------------------
// Kernel 1: three 1x1 convs on the mid depth slice. fp32 in, f16 store.
// Output layout: [b][hw][16] (channel-inner) so patchify can vector-load.
// ---------------------------------------------------------------------------
__global__ __launch_bounds__(256) void k_conv_qkv(
    const float* __restrict__ s, const float* __restrict__ g,
    const float* __restrict__ g_w, const float* __restrict__ g_b,
    const float* __restrict__ th_w, const float* __restrict__ th_b,
    const float* __restrict__ ph_w, const float* __restrict__ ph_b,
    unsigned short* __restrict__ b1, unsigned short* __restrict__ b2,
    unsigned short* __restrict__ b3)
{
    __shared__ float wq[ICn * C_], wt[ICn * C_], wp[ICn * C_];
    for (int i = threadIdx.x; i < ICn * C_; i += 256) {
        wq[i] = g_w[i]; wt[i] = th_w[i]; wp[i] = ph_w[i];
    }
    __syncthreads();

    int t = blockIdx.x * 256 + threadIdx.x;     // B_*HW_ = 65536 threads
    int hw = t & (HW_ - 1);
    int b  = t >> 14;

    float aq[ICn], at[ICn], ap[ICn];
#pragma unroll
    for (int o = 0; o < ICn; o++) { aq[o] = 0.f; at[o] = 0.f; ap[o] = 0.f; }

    for (int cc = 0; cc < C_; cc++) {
        size_t idx = ((size_t)((b * C_ + cc) * D_) + MID_) * HW_ + hw;
        float sv = s[idx];
        float gv = g[idx];
#pragma unroll
        for (int o = 0; o < ICn; o++) {
            aq[o] = fmaf(wq[o * C_ + cc], sv, aq[o]);
            at[o] = fmaf(wt[o * C_ + cc], gv, at[o]);
            ap[o] = fmaf(wp[o * C_ + cc], gv, ap[o]);
        }
    }
    unsigned short tq[16], tt[16], tp[16];
#pragma unroll
    for (int o = 0; o < ICn; o++) {
        tq[o] = f2h(aq[o] + g_b[o]);
        tt[o] = f2h(at[o] + th_b[o]);
        tp[o] = f2h(ap[o] + ph_b[o]);
    }
    size_t base = (size_t)(b * HW_ + hw) * 16;
    *(uint4*)(b1 + base) = *(uint4*)tq; *(uint4*)(b1 + base + 8) = *(uint4*)(tq + 8);
    *(uint4*)(b2 + base) = *(uint4*)tt; *(uint4*)(b2 + base + 8) = *(uint4*)(tt + 8);
    *(uint4*)(b3 + base) = *(uint4*)tp; *(uint4*)(b3 + base + 8) = *(uint4*)(tp + 8);
}

// ---------------------------------------------------------------------------
// Kernel 2: patch extraction. Feature axis reordered: f' = pos*16 + c.
//   q  [b][l][160]  (320B rows, zero-pad [144,160))
//   kr [b][l][192]  (384B rows, zero-pad [144,160), [160,192) don't-care)
//   vt [b][192][L]  (rows 144-191 never written/read)
// ---------------------------------------------------------------------------
__global__ __launch_bounds__(256) void k_patchify(
    const unsigned short* __restrict__ b1, const unsigned short* __restrict__ b2,
    const unsigned short* __restrict__ b3,
    unsigned short* __restrict__ q, unsigned short* __restrict__ kr,
    unsigned short* __restrict__ vt)
{
    int t = blockIdx.x * 256 + threadIdx.x;     // B_*9*L_ = 147456
    int l = t & (L_ - 1);
    int rest = t >> 12;         // b*9 + pos, 0..35
    int b = rest / 9;
    int pos = rest - b * 9;
    int ki = pos / 3, kj = pos - ki * 3;
    int ph = l >> 6, pw = l & 63;
    int hr = 2 * ph - 1 + ki;
    int wc = 2 * pw - 1 + kj;

    union { uint4 v[2]; unsigned short u[16]; } qd, vd, kd;
    uint4 z4 = {0u, 0u, 0u, 0u};
    qd.v[0] = qd.v[1] = z4; vd.v[0] = vd.v[1] = z4; kd.v[0] = kd.v[1] = z4;
    if (hr >= 0 && hr < H_ && wc >= 0 && wc < W_) {
        size_t base = (size_t)(b * HW_ + hr * W_ + wc) * 16;
        qd.v[0] = *(const uint4*)(b1 + base); qd.v[1] = *(const uint4*)(b1 + base + 8);
        vd.v[0] = *(const uint4*)(b2 + base); vd.v[1] = *(const uint4*)(b2 + base + 8);
        kd.v[0] = *(const uint4*)(b3 + base); kd.v[1] = *(const uint4*)(b3 + base + 8);
    }
    size_t qb = ((size_t)b * L_ + l) * FP_ + pos * 16;
    size_t kb = ((size_t)b * L_ + l) * KRS_ + pos * 16;
    *(uint4*)(q + qb) = qd.v[0];  *(uint4*)(q + qb + 8) = qd.v[1];
    *(uint4*)(kr + kb) = kd.v[0]; *(uint4*)(kr + kb + 8) = kd.v[1];

    size_t vbase = ((size_t)(b * VTR_) + pos * 16) * L_ + l;
#pragma unroll
    for (int c = 0; c < 16; c++) vt[vbase + (size_t)c * L_] = vd.u[c];

    if (pos == 0) {   // zero-pad f in [144,160) for q and kr
        size_t pq = ((size_t)b * L_ + l) * FP_ + F_;
        size_t pk = ((size_t)b * L_ + l) * KRS_ + F_;
        *(uint4*)(q + pq) = z4;  *(uint4*)(q + pq + 8) = z4;
        *(uint4*)(kr + pk) = z4; *(uint4*)(kr + pk + 8) = z4;
    }
}

// ---------------------------------------------------------------------------
// Kernel 3: MFMA flash attention (v_mfma_f32_16x16x32_f16).
//   Block = 512 thr (8 waves), TM = 128 rows (16/wave), TN = 64 keys.
//   Key-split = 2 -> grid 256 = 1 block/CU, 2 waves/SIMD.
//   Staging: global_load_lds (16B) into double-buffered LDS, counted
//   vmcnt(6) + raw barriers (loads stay in flight across barriers; no
//   staging VGPRs -> no spills). LDS XOR-swizzle applied by pre-swizzling
//   the GLOBAL source address (linear LDS dest) and XOR-ing on ds_read.
// ---------------------------------------------------------------------------
#define TN_  64
#define NT_  32            // key tiles per split: (L_/TN_)/2
#define KSB  384           // Ks row stride bytes
#define KTB  24576         // bytes per K tile in LDS (64*384)
#define VTB  24576         // bytes per V tile in LDS (192*128)

__global__ __launch_bounds__(512, 1) void k_attn_mfma(
    const unsigned short* __restrict__ q, const unsigned short* __restrict__ kr,
    const unsigned short* __restrict__ vt,
    float* __restrict__ pacc, float* __restrict__ pml)
{
    __shared__ unsigned short Ks[2 * 64 * KRS_];   // dbuf [key][192], 384B rows
    __shared__ unsigned short Vs[2 * VTR_ * TN_];  // dbuf [f][64], 128B rows
    __shared__ unsigned short Ps[8][16 * TN_];     // per-wave P [q][key]

    const int t    = threadIdx.x;
    const int w    = t >> 6;
    const int lane = t & 63;
    const int l15  = lane & 15;
    const int l4   = lane >> 4;

    const int rb    = blockIdx.x & 31;
    const int split = (blockIdx.x >> 5) & 1;
    const int b     = blockIdx.x >> 6;
    const int row0  = rb * 128 + w * 16;          // wave's first query row

    // per-lane staging source offsets (in shorts, within a tile)
    int ksrc[3], vsrc[3];
#pragma unroll
    for (int it = 0; it < 3; it++) {
        int n = t + it * 512;                     // K: [0,1536) chunks of 16B
        int krow = n / 24, kc = n - krow * 24;    // 24 chunks per 384B row
        ksrc[it] = krow * KRS_ + ((kc ^ (krow & 7)) * 8);
        int vrow = n >> 3, vc = n & 7;            // V: 8 chunks per 128B row
        vsrc[it] = vrow * L_ + ((vc ^ (vrow & 7)) * 8);
    }

    const unsigned short* kg = kr + (size_t)b * L_ * KRS_;
    const unsigned short* vg = vt + (size_t)b * VTR_ * L_;

    // Q fragments (B-operand: col = q = l15, k-chunk = l4*8), kept in regs.
    half8_t qf[5];
#pragma unroll
    for (int ks = 0; ks < 5; ks++) {
        size_t off = ((size_t)b * L_ + row0 + l15) * FP_ + ks * 32 + l4 * 8;
        qf[ks] = *(const half8_t*)(q + off);
    }

    f32x4_t zero4 = {0.f, 0.f, 0.f, 0.f};
    f32x4_t acc[9];
#pragma unroll
    for (int ft = 0; ft < 9; ft++) acc[ft] = zero4;

    float m_run = -3.0e38f;
    float l_run = 0.f;

    unsigned short* Pw = Ps[w];
    const int kt0 = split * NT_;

    auto stage = [&](int kt, int buf) {
        const unsigned short* ktg = kg + (size_t)kt * TN_ * KRS_;
        const unsigned short* vtg = vg + (size_t)kt * TN_;
        char* kl = (char*)Ks + buf * KTB + w * 1024;
        char* vl = (char*)Vs + buf * VTB + w * 1024;
#pragma unroll
        for (int it = 0; it < 3; it++)
            __builtin_amdgcn_global_load_lds(
                (const __attribute__((address_space(1))) unsigned int*)(ktg + ksrc[it]),
                (__attribute__((address_space(3))) unsigned int*)(kl + it * 8192),
                16, 0, 0);
#pragma unroll
        for (int it = 0; it < 3; it++)
            __builtin_amdgcn_global_load_lds(
                (const __attribute__((address_space(1))) unsigned int*)(vtg + vsrc[it]),
                (__attribute__((address_space(3))) unsigned int*)(vl + it * 8192),
                16, 0, 0);
    };

    stage(kt0, 0);

    for (int kt = kt0; kt < kt0 + NT_; kt++) {
        const int cur = (kt - kt0) & 1;
        if (kt + 1 < kt0 + NT_) {
            stage(kt + 1, cur ^ 1);
            asm volatile("s_waitcnt vmcnt(6)" ::: "memory");   // tile kt resident
        } else {
            asm volatile("s_waitcnt vmcnt(0)" ::: "memory");
        }
        __builtin_amdgcn_s_barrier();            // all waves: buf[cur] staged
        __builtin_amdgcn_sched_barrier(0);

        const char* Kc = (const char*)Ks + cur * KTB;
        const char* Vc = (const char*)Vs + cur * VTB;

        // ---- S^T = K Q^T: D[key][q], 4 key-tiles, K = 160 (5x32)
        f32x4_t sacc[4];
#pragma unroll
        for (int mt = 0; mt < 4; mt++) sacc[mt] = zero4;

#pragma unroll
        for (int ks = 0; ks < 5; ks++) {
            half8_t af[4];
#pragma unroll
            for (int mt = 0; mt < 4; mt++) {
                int row = mt * 16 + l15;
                af[mt] = *(const half8_t*)(Kc + row * KSB +
                            ((ks * 64 + l4 * 16) ^ ((l15 & 7) << 4)));
            }
            __builtin_amdgcn_s_setprio(1);
#pragma unroll
            for (int mt = 0; mt < 4; mt++)
                sacc[mt] = __builtin_amdgcn_mfma_f32_16x16x32_f16(
                    af[mt], qf[ks], sacc[mt], 0, 0, 0);
            __builtin_amdgcn_s_setprio(0);
        }
#pragma unroll
        for (int mt = 0; mt < 4; mt++) sacc[mt] *= SC_;

        // ---- online softmax, query q = l15 (lane holds keys mt*16+4*l4+r)
        float pm = sacc[0][0];
#pragma unroll
        for (int mt = 0; mt < 4; mt++)
#pragma unroll
            for (int r = 0; r < 4; r++) pm = fmaxf(pm, sacc[mt][r]);
        pm = fmaxf(pm, __shfl_xor(pm, 16, 64));
        pm = fmaxf(pm, __shfl_xor(pm, 32, 64));
        float mn = fmaxf(m_run, pm);
        float alpha_q = __builtin_amdgcn_exp2f(m_run - mn);
        m_run = mn;
        float ps = 0.f;
#pragma unroll
        for (int mt = 0; mt < 4; mt++) {
            float e0 = __builtin_amdgcn_exp2f(sacc[mt][0] - mn);
            float e1 = __builtin_amdgcn_exp2f(sacc[mt][1] - mn);
            float e2 = __builtin_amdgcn_exp2f(sacc[mt][2] - mn);
            float e3 = __builtin_amdgcn_exp2f(sacc[mt][3] - mn);
            ps += e0 + e1 + e2 + e3;
            ushort4 pk;                      // keys mt*16 + 4*l4 + {0..3}
            pk.x = f2h(e0); pk.y = f2h(e1); pk.z = f2h(e2); pk.w = f2h(e3);
            *(ushort4*)((char*)Pw + l15 * 128 +
                        ((mt * 32 + l4 * 8) ^ ((l15 & 7) << 4))) = pk;
        }
        ps += __shfl_xor(ps, 16, 64);
        ps += __shfl_xor(ps, 32, 64);
        l_run = l_run * alpha_q + ps;

        // ---- rescale acc by alpha of its own row q' = 4*l4 + r
        f32x4_t av;
#pragma unroll
        for (int r = 0; r < 4; r++)
            av[r] = __shfl(alpha_q, (lane & 48) | (4 * l4 + r), 64);
#pragma unroll
        for (int ft = 0; ft < 9; ft++)
#pragma unroll
            for (int r = 0; r < 4; r++) acc[ft][r] *= av[r];

        // ---- PV: D[q][f'] += P V   (A = P from LDS, B = V from LDS)
#pragma unroll
        for (int ks = 0; ks < 2; ks++) {
            half8_t pa = *(const half8_t*)((const char*)Pw + l15 * 128 +
                            ((ks * 64 + l4 * 16) ^ ((l15 & 7) << 4)));
            __builtin_amdgcn_s_setprio(1);
#pragma unroll
            for (int ft = 0; ft < 9; ft++) {
                int f = ft * 16 + l15;
                half8_t vbf = *(const half8_t*)(Vc + f * 128 +
                            ((ks * 64 + l4 * 16) ^ ((l15 & 7) << 4)));
                acc[ft] = __builtin_amdgcn_mfma_f32_16x16x32_f16(
                    pa, vbf, acc[ft], 0, 0, 0);
            }
            __builtin_amdgcn_s_setprio(0);
        }

        __builtin_amdgcn_sched_barrier(0);       // keep reads above barrier
        __builtin_amdgcn_s_barrier();            // buf[cur] free for overwrite
    }

    // ---- epilogue: store unnormalized acc + (m,l); k_combine normalizes
    const size_t prow0 = ((size_t)split * B_ + b) * L_ + row0;
#pragma unroll
    for (int r = 0; r < 4; r++) {
        size_t R = prow0 + 4 * l4 + r;
#pragma unroll
        for (int ft = 0; ft < 9; ft++)
            pacc[R * F_ + ft * 16 + l15] = acc[ft][r];
    }
    if (l4 == 0) {
        size_t R = prow0 + l15;
        pml[R * 2 + 0] = m_run;
        pml[R * 2 + 1] = l_run;
    }
}

// ---------------------------------------------------------------------------
// Kernel 3b: merge the two key-split partials -> zi [b][l][144] fp32.
// ---------------------------------------------------------------------------
__global__ __launch_bounds__(256) void k_combine(
    const float* __restrict__ pacc, const float* __restrict__ pml,
    float* __restrict__ zi)
{
    int tg = blockIdx.x * 256 + threadIdx.x;     // B_*L_*36 = 589824
    int row = tg / 36;
    int c = tg - row * 36;
    float m0 = pml[(size_t)row * 2],                    l0 = pml[(size_t)row * 2 + 1];
    float m1 = pml[((size_t)(B_ * L_) + row) * 2],      l1 = pml[((size_t)(B_ * L_) + row) * 2 + 1];
    float mm = fmaxf(m0, m1);
    float w0 = __builtin_amdgcn_exp2f(m0 - mm);
    float w1 = __builtin_amdgcn_exp2f(m1 - mm);
    float inv = 1.f / (l0 * w0 + l1 * w1);
    float4 a0 = *(const float4*)&pacc[(size_t)row * F_ + c * 4];
    float4 a1 = *(const float4*)&pacc[((size_t)(B_ * L_) + row) * F_ + c * 4];
    float4 o;
    o.x = (a0.x * w0 + a1.x * w1) * inv;
    o.y = (a0.y * w0 + a1.y * w1) * inv;
    o.z = (a0.z * w0 + a1.z * w1) * inv;
    o.w = (a0.w * w0 + a1.w * w1) * inv;
    *(float4*)&zi[(size_t)row * F_ + c * 4] = o;
}

// ---------------------------------------------------------------------------
// Kernel 4: fold (overlap-add) + mask normalization. One thread per (b,hw),
// all 16 channels at once via float4 loads (f' = pos*16 + c layout).
// z output: [b][ic][hw].
// ---------------------------------------------------------------------------
__global__ __launch_bounds__(256) void k_fold(
    const float* __restrict__ zi, float* __restrict__ z)
{
    int t = blockIdx.x * 256 + threadIdx.x;   // B_*HW_ = 65536
    int hw = t & (HW_ - 1);
    int b  = t >> 14;
    int h = hw >> 7, w = hw & 127;
    int hh = h + 1, ww = w + 1;

    int iArr[2], phArr[2], nh = 0;
#pragma unroll
    for (int i = 0; i < 3; i++) {
        int u = hh - i;
        if (u >= 0 && (u & 1) == 0 && (u >> 1) < HP_) { iArr[nh] = i; phArr[nh] = u >> 1; nh++; }
    }
    int jArr[2], pwArr[2], nw = 0;
#pragma unroll
    for (int j = 0; j < 3; j++) {
        int u = ww - j;
        if (u >= 0 && (u & 1) == 0 && (u >> 1) < HP_) { jArr[nw] = j; pwArr[nw] = u >> 1; nw++; }
    }
    float acc[16];
#pragma unroll
    for (int k = 0; k < 16; k++) acc[k] = 0.f;

    for (int a = 0; a < nh; a++)
        for (int c2 = 0; c2 < nw; c2++) {
            int l = phArr[a] * 64 + pwArr[c2];
            int pos = iArr[a] * 3 + jArr[c2];
            const float4* zp = (const float4*)(zi + ((size_t)b * L_ + l) * F_ + pos * 16);
            float4 a0 = zp[0], a1 = zp[1], a2 = zp[2], a3 = zp[3];
            acc[0] += a0.x; acc[1] += a0.y; acc[2]  += a0.z; acc[3]  += a0.w;
            acc[4] += a1.x; acc[5] += a1.y; acc[6]  += a1.z; acc[7]  += a1.w;
            acc[8] += a2.x; acc[9] += a2.y; acc[10] += a2.z; acc[11] += a2.w;
            acc[12] += a3.x; acc[13] += a3.y; acc[14] += a3.z; acc[15] += a3.w;
        }
    float inv = 1.0f / (float)(nh * nw);
#pragma unroll
    for (int ic = 0; ic < 16; ic++)
        z[((size_t)(b * ICn + ic) << 14) + hw] = acc[ic] * inv;
}

// ---------------------------------------------------------------------------
// Kernel 5: out = s + W_w @ z + W_bias, broadcast over D. One thread per
// (b,c,hw8): compute W.z once, reuse across the 8 d-planes.
// ---------------------------------------------------------------------------
__global__ __launch_bounds__(256) void k_out(
    const float* __restrict__ s, const float* __restrict__ z,
    const float* __restrict__ Ww, const float* __restrict__ Wb,
    float* __restrict__ out)
{
    int t = blockIdx.x * 256 + threadIdx.x;   // B_*C_*HW_/8 = 524288 threads
    size_t e0 = (size_t)t * 8;
    int hw = (int)(e0 & (HW_ - 1));
    int c  = (int)((e0 >> 14) & 63);
    int b  = (int)(e0 >> 20);

    float bias = Wb[c];
    float acc[8];
#pragma unroll
    for (int i = 0; i < 8; i++) acc[i] = bias;

    const float* zb = z + ((size_t)(b * ICn) << 14) + hw;
#pragma unroll
    for (int ic = 0; ic < ICn; ic++) {
        float wv = Ww[c * ICn + ic];
        const float4* zp = (const float4*)(zb + ((size_t)ic << 14));
        float4 z0 = zp[0], z1 = zp[1];
        acc[0] = fmaf(wv, z0.x, acc[0]); acc[1] = fmaf(wv, z0.y, acc[1]);
        acc[2] = fmaf(wv, z0.z, acc[2]); acc[3] = fmaf(wv, z0.w, acc[3]);
        acc[4] = fmaf(wv, z1.x, acc[4]); acc[5] = fmaf(wv, z1.y, acc[5]);
        acc[6] = fmaf(wv, z1.z, acc[6]); acc[7] = fmaf(wv, z1.w, acc[7]);
    }

#pragma unroll
    for (int d = 0; d < D_; d++) {
        size_t off = (((size_t)(b * C_ + c) * D_ + d) << 14) + hw;
        const float4* sp = (const float4*)(s + off);
        float4 s0 = sp[0], s1 = sp[1];
        float4 o0 = make_float4(s0.x + acc[0], s0.y + acc[1], s0.z + acc[2], s0.w + acc[3]);
        float4 o1 = make_float4(s1.x + acc[4], s1.y + acc[5], s1.z + acc[6], s1.w + acc[7]);
        float4* op = (float4*)(out + off);
        op[0] = o0; op[1] = o1;
    }
}

// ---------------------------------------------------------------------------
extern "C" void kernel_launch(void* const* d_in, const int* in_sizes, int n_in,
                              void* d_out, int out_size, void* d_ws, size_t ws_size,
                              hipStream_t stream)
{
    (void)in_sizes; (void)n_in; (void)out_size; (void)ws_size;
    const float* s    = (const float*)d_in[0];
    const float* g    = (const float*)d_in[1];
    const float* g_w  = (const float*)d_in[2];
    const float* g_b  = (const float*)d_in[3];
    const float* th_w = (const float*)d_in[4];
    const float* th_b = (const float*)d_in[5];
    const float* ph_w = (const float*)d_in[6];
    const float* ph_b = (const float*)d_in[7];
    const float* W_w  = (const float*)d_in[8];
    const float* W_b  = (const float*)d_in[9];
    float* out = (float*)d_out;

    // Workspace layout (high-water ~41.3 MB):
    //   [0, 6M)            b1,b2,b3 f16 [b][hw][16] (dead after patchify)
    //   [6291456,11534336)   q  f16 [b][l][160]
    //   [11534336,17825792)  kr f16 [b][l][192]
    //   [17825792,24117248)  vt f16 [b][192][L]
    //   [24117248,42991616)  pacc fp32 [2][b][l][144]
    //   [42991616,43253760)  pml  fp32 [2][b][l][2]
    //   overlays (post-attn): zi fp32 at 0 (9.44M), zz fp32 at 9437184 (4M)
    char* base = (char*)d_ws;
    const size_t CONV_B = 2097152;
    unsigned short* b1 = (unsigned short*)(base);
    unsigned short* b2 = (unsigned short*)(base + CONV_B);
    unsigned short* b3 = (unsigned short*)(base + 2 * CONV_B);
    unsigned short* qq = (unsigned short*)(base + 6291456);
    unsigned short* kk = (unsigned short*)(base + 11534336);
    unsigned short* vv = (unsigned short*)(base + 17825792);
    float*          pacc = (float*)(base + 24117248);
    float*          pml  = (float*)(base + 42991616);
    float*          zi   = (float*)(base);             // overlay: conv planes + q head (dead)
    float*          zz   = (float*)(base + 9437184);   // overlay: q tail / kr head (dead)

    hipLaunchKernelGGL(k_conv_qkv, dim3(256),   dim3(256), 0, stream,
                       s, g, g_w, g_b, th_w, th_b, ph_w, ph_b, b1, b2, b3);
    hipLaunchKernelGGL(k_patchify, dim3(576),   dim3(256), 0, stream, b1, b2, b3, qq, kk, vv);
    hipLaunchKernelGGL(k_attn_mfma, dim3(256),  dim3(512), 0, stream, qq, kk, vv, pacc, pml);
    hipLaunchKernelGGL(k_combine,  dim3(2304),  dim3(256), 0, stream, pacc, pml, zi);
    hipLaunchKernelGGL(k_fold,     dim3(256),   dim3(256), 0, stream, zi, zz);
    hipLaunchKernelGGL(k_out,      dim3(2048),  dim3(256), 0, stream, s, zz, W_w, W_b, out);
}